// Round 5
// baseline (683.295 us; speedup 1.0000x reference)
//
#include <hip/hip_runtime.h>
#include <hip/hip_bf16.h>

static constexpr int E_ = 5000;
static constexpr int N_ = 200000;
static constexpr int D_ = 128;
// 1 / (3 * sqrt(128))
static constexpr float INV_ = 0.029462782549439484f;

typedef float vf4 __attribute__((ext_vector_type(4)));  // clang-native for nontemporal builtin

// Zero-fill both adjacency matrices (fp32) and write 1.0 on each diagonal.
// Each thread stores 64 B (16 floats = 4 x vf4), nontemporal to avoid
// polluting L2 ahead of the triple kernel. E*E = 25e6 is divisible by 16,
// so a chunk never straddles the two graphs; a 16-float chunk contains at
// most one diagonal element (diag stride E+1 = 5001 > 16).
__global__ __launch_bounds__(256) void init_kernel(float* __restrict__ out,
                                                   int nthreads) {
    int c = blockIdx.x * 256 + threadIdx.x;
    if (c >= nthreads) return;
    int base = c * 16;                 // flat float index, < 50e6 (fits int)
    int local = base % (E_ * E_);      // position within one graph's E*E
    float v[16];
    #pragma unroll
    for (int i = 0; i < 16; ++i) v[i] = 0.f;
    int r = local % (E_ + 1);
    int k = (r == 0) ? 0 : (E_ + 1) - r;
    if (k < 16) v[k] = 1.0f;
    vf4* dst = reinterpret_cast<vf4*>(out + base);
    const vf4* src = reinterpret_cast<const vf4*>(v);
    #pragma unroll
    for (int i = 0; i < 4; ++i)
        __builtin_nontemporal_store(src[i], dst + i);
}

// 8 lanes per triple (8 triples per wave). Lane sub-index s in [0,8)
// handles dims 16s..16s+15 via four float4 loads. Covers BOTH graphs in
// one dispatch: triples [0,N) are sr, [N,2N) are tg. N % 8 == 0 so all 8
// triples in a wave belong to the same graph (gB is wave-uniform).
__global__ __launch_bounds__(256) void triple_kernel(
        const float* __restrict__ ent_a, const float* __restrict__ rel_a,
        const float* __restrict__ relw_a,
        const float* __restrict__ conf_a, const float* __restrict__ imp_a,
        const float* __restrict__ pca_a,
        const int* __restrict__ head_a, const int* __restrict__ tail_a,
        const int* __restrict__ ridx_a,
        const float* __restrict__ ent_b, const float* __restrict__ rel_b,
        const float* __restrict__ relw_b,
        const float* __restrict__ conf_b, const float* __restrict__ imp_b,
        const float* __restrict__ pca_b,
        const int* __restrict__ head_b, const int* __restrict__ tail_b,
        const int* __restrict__ ridx_b,
        float* __restrict__ out)         // [2, E, E] f32
{
    int gtid = blockIdx.x * 256 + threadIdx.x;
    int wave = gtid >> 6;
    int lane = gtid & 63;
    int sub  = lane & 7;                // lane within the 8-group
    int trip = wave * 8 + (lane >> 3);  // global triple id in [0, 2N)
    if (trip >= 2 * N_) return;

    bool gB = (trip >= N_);             // wave-uniform (N % 8 == 0)
    int  w  = gB ? (trip - N_) : trip;

    const float* ent  = gB ? ent_b  : ent_a;
    const float* rel  = gB ? rel_b  : rel_a;
    const float* relw = gB ? relw_b : relw_a;
    const float* conf = gB ? conf_b : conf_a;
    const float* imp  = gB ? imp_b  : imp_a;
    const float* pca  = gB ? pca_b  : pca_a;
    const int*  head  = gB ? head_b : head_a;
    const int*  tail  = gB ? tail_b : tail_a;
    const int*  ridx  = gB ? ridx_b : ridx_a;
    float* o = out + (gB ? (long long)E_ * E_ : 0);

    int h = head[w];
    int t = tail[w];
    int r = ridx[w];

    int d0 = sub * 16;
    const float4* hp = reinterpret_cast<const float4*>(ent + h * D_ + d0);
    const float4* tp = reinterpret_cast<const float4*>(ent + t * D_ + d0);
    const float4* rp = reinterpret_cast<const float4*>(rel + r * D_ + d0);

    float s = 0.f;
    #pragma unroll
    for (int i = 0; i < 4; ++i) {
        float4 hv = hp[i], tv = tp[i], rv = rp[i];
        s += fabsf(hv.x + rv.x - tv.x) + fabsf(hv.y + rv.y - tv.y)
           + fabsf(hv.z + rv.z - tv.z) + fabsf(hv.w + rv.w - tv.w);
    }

    // reduce across the 8-lane group (xor masks < 8 stay in-group)
    s += __shfl_xor(s, 4, 64);
    s += __shfl_xor(s, 2, 64);
    s += __shfl_xor(s, 1, 64);

    if (sub == 0) {
        float tvs = 1.0f - s * INV_;
        int pos = h * E_ + t;                    // < 25e6, fits int
        float val = conf[pos] * imp[pos]
                  * (0.3f * pca[pos] + 0.3f * tvs + 0.4f * relw[r]);
        if (h == t) val += 1.0f;                 // overwrite init's diagonal 1.0
        o[pos] = val;                            // unique (h,t) -> plain store
    }
}

extern "C" void kernel_launch(void* const* d_in, const int* in_sizes, int n_in,
                              void* d_out, int out_size, void* d_ws, size_t ws_size,
                              hipStream_t stream) {
    const float* ent_sr  = (const float*)d_in[0];
    const float* ent_tg  = (const float*)d_in[1];
    const float* rel_sr  = (const float*)d_in[2];
    const float* rel_tg  = (const float*)d_in[3];
    const float* relw_sr = (const float*)d_in[4];
    const float* relw_tg = (const float*)d_in[5];
    const float* conf_sr = (const float*)d_in[6];
    const float* imp_sr  = (const float*)d_in[7];
    const float* pca_sr  = (const float*)d_in[8];
    const float* conf_tg = (const float*)d_in[9];
    const float* imp_tg  = (const float*)d_in[10];
    const float* pca_tg  = (const float*)d_in[11];
    const int* head_sr = (const int*)d_in[12];
    const int* tail_sr = (const int*)d_in[13];
    const int* rel_i_sr = (const int*)d_in[14];
    const int* head_tg = (const int*)d_in[15];
    const int* tail_tg = (const int*)d_in[16];
    const int* rel_i_tg = (const int*)d_in[17];

    float* out = (float*)d_out;

    const int total = 2 * E_ * E_;           // 50,000,000 floats
    const int nthreads = total / 16;         // 3,125,000
    int init_blocks = (nthreads + 255) / 256;
    init_kernel<<<init_blocks, 256, 0, stream>>>(out, nthreads);

    // 2N triples, 8 per wave, 4 waves per block
    int waves = (2 * N_) / 8;                // 50,000
    int tri_blocks = (waves + 3) / 4;        // 12,500
    triple_kernel<<<tri_blocks, 256, 0, stream>>>(
        ent_sr, rel_sr, relw_sr, conf_sr, imp_sr, pca_sr,
        head_sr, tail_sr, rel_i_sr,
        ent_tg, rel_tg, relw_tg, conf_tg, imp_tg, pca_tg,
        head_tg, tail_tg, rel_i_tg,
        out);
}

// Round 6
// 598.752 us; speedup vs baseline: 1.1412x; 1.1412x over previous
//
#include <hip/hip_runtime.h>
#include <hip/hip_bf16.h>

static constexpr int E_ = 5000;
static constexpr int N_ = 200000;
static constexpr int D_ = 128;
// 1 / (3 * sqrt(128))
static constexpr float INV_ = 0.029462782549439484f;

// Zero-fill both adjacency matrices (fp32) and write 1.0 on each diagonal.
// Each thread stores 64 B (16 floats = 4 x float4) with PLAIN stores --
// L2 write-combining is what gives fill-rate BW here. (Round-5 lesson:
// nontemporal stores doubled WRITE_SIZE to 427 MB and dropped BW to
// 2.75 TB/s -- never use nt stores for contiguous streaming fills.)
// E*E = 25e6 is divisible by 16, so a chunk never straddles the two
// graphs; a 16-float chunk contains at most one diagonal element
// (diag stride E+1 = 5001 > 16).
__global__ __launch_bounds__(256) void init_kernel(float* __restrict__ out,
                                                   int nthreads) {
    int c = blockIdx.x * 256 + threadIdx.x;
    if (c >= nthreads) return;
    int base = c * 16;                 // flat float index, < 50e6 (fits int)
    int local = base % (E_ * E_);      // position within one graph's E*E
    float v[16];
    #pragma unroll
    for (int i = 0; i < 16; ++i) v[i] = 0.f;
    int r = local % (E_ + 1);
    int k = (r == 0) ? 0 : (E_ + 1) - r;
    if (k < 16) v[k] = 1.0f;
    float4* dst = reinterpret_cast<float4*>(out + base);
    const float4* src = reinterpret_cast<const float4*>(v);
    #pragma unroll
    for (int i = 0; i < 4; ++i) dst[i] = src[i];
}

// 8 lanes per triple (8 triples per wave). Lane sub-index s in [0,8)
// handles dims 16s..16s+15 via four float4 loads. Covers BOTH graphs in
// one dispatch: triples [0,N) are sr, [N,2N) are tg. N % 8 == 0 so all 8
// triples in a wave belong to the same graph (gB is wave-uniform).
__global__ __launch_bounds__(256) void triple_kernel(
        const float* __restrict__ ent_a, const float* __restrict__ rel_a,
        const float* __restrict__ relw_a,
        const float* __restrict__ conf_a, const float* __restrict__ imp_a,
        const float* __restrict__ pca_a,
        const int* __restrict__ head_a, const int* __restrict__ tail_a,
        const int* __restrict__ ridx_a,
        const float* __restrict__ ent_b, const float* __restrict__ rel_b,
        const float* __restrict__ relw_b,
        const float* __restrict__ conf_b, const float* __restrict__ imp_b,
        const float* __restrict__ pca_b,
        const int* __restrict__ head_b, const int* __restrict__ tail_b,
        const int* __restrict__ ridx_b,
        float* __restrict__ out)         // [2, E, E] f32
{
    int gtid = blockIdx.x * 256 + threadIdx.x;
    int wave = gtid >> 6;
    int lane = gtid & 63;
    int sub  = lane & 7;                // lane within the 8-group
    int trip = wave * 8 + (lane >> 3);  // global triple id in [0, 2N)
    if (trip >= 2 * N_) return;

    bool gB = (trip >= N_);             // wave-uniform (N % 8 == 0)
    int  w  = gB ? (trip - N_) : trip;

    const float* ent  = gB ? ent_b  : ent_a;
    const float* rel  = gB ? rel_b  : rel_a;
    const float* relw = gB ? relw_b : relw_a;
    const float* conf = gB ? conf_b : conf_a;
    const float* imp  = gB ? imp_b  : imp_a;
    const float* pca  = gB ? pca_b  : pca_a;
    const int*  head  = gB ? head_b : head_a;
    const int*  tail  = gB ? tail_b : tail_a;
    const int*  ridx  = gB ? ridx_b : ridx_a;
    float* o = out + (gB ? (long long)E_ * E_ : 0);

    int h = head[w];
    int t = tail[w];
    int r = ridx[w];

    int d0 = sub * 16;
    const float4* hp = reinterpret_cast<const float4*>(ent + h * D_ + d0);
    const float4* tp = reinterpret_cast<const float4*>(ent + t * D_ + d0);
    const float4* rp = reinterpret_cast<const float4*>(rel + r * D_ + d0);

    float s = 0.f;
    #pragma unroll
    for (int i = 0; i < 4; ++i) {
        float4 hv = hp[i], tv = tp[i], rv = rp[i];
        s += fabsf(hv.x + rv.x - tv.x) + fabsf(hv.y + rv.y - tv.y)
           + fabsf(hv.z + rv.z - tv.z) + fabsf(hv.w + rv.w - tv.w);
    }

    // reduce across the 8-lane group (xor masks < 8 stay in-group)
    s += __shfl_xor(s, 4, 64);
    s += __shfl_xor(s, 2, 64);
    s += __shfl_xor(s, 1, 64);

    if (sub == 0) {
        float tvs = 1.0f - s * INV_;
        int pos = h * E_ + t;                    // < 25e6, fits int
        float val = conf[pos] * imp[pos]
                  * (0.3f * pca[pos] + 0.3f * tvs + 0.4f * relw[r]);
        if (h == t) val += 1.0f;                 // overwrite init's diagonal 1.0
        o[pos] = val;                            // unique (h,t) -> plain store
    }
}

extern "C" void kernel_launch(void* const* d_in, const int* in_sizes, int n_in,
                              void* d_out, int out_size, void* d_ws, size_t ws_size,
                              hipStream_t stream) {
    const float* ent_sr  = (const float*)d_in[0];
    const float* ent_tg  = (const float*)d_in[1];
    const float* rel_sr  = (const float*)d_in[2];
    const float* rel_tg  = (const float*)d_in[3];
    const float* relw_sr = (const float*)d_in[4];
    const float* relw_tg = (const float*)d_in[5];
    const float* conf_sr = (const float*)d_in[6];
    const float* imp_sr  = (const float*)d_in[7];
    const float* pca_sr  = (const float*)d_in[8];
    const float* conf_tg = (const float*)d_in[9];
    const float* imp_tg  = (const float*)d_in[10];
    const float* pca_tg  = (const float*)d_in[11];
    const int* head_sr = (const int*)d_in[12];
    const int* tail_sr = (const int*)d_in[13];
    const int* rel_i_sr = (const int*)d_in[14];
    const int* head_tg = (const int*)d_in[15];
    const int* tail_tg = (const int*)d_in[16];
    const int* rel_i_tg = (const int*)d_in[17];

    float* out = (float*)d_out;

    const int total = 2 * E_ * E_;           // 50,000,000 floats
    const int nthreads = total / 16;         // 3,125,000
    int init_blocks = (nthreads + 255) / 256;
    init_kernel<<<init_blocks, 256, 0, stream>>>(out, nthreads);

    // 2N triples, 8 per wave, 4 waves per block
    int waves = (2 * N_) / 8;                // 50,000
    int tri_blocks = (waves + 3) / 4;        // 12,500
    triple_kernel<<<tri_blocks, 256, 0, stream>>>(
        ent_sr, rel_sr, relw_sr, conf_sr, imp_sr, pca_sr,
        head_sr, tail_sr, rel_i_sr,
        ent_tg, rel_tg, relw_tg, conf_tg, imp_tg, pca_tg,
        head_tg, tail_tg, rel_i_tg,
        out);
}